// Round 10
// baseline (868.702 us; speedup 1.0000x reference)
//
#include <hip/hip_runtime.h>
#include <hip/hip_bf16.h>

#define N_NODES 100000
#define N_EDGES 1600000
#define DIM     128
#define N_LAYERS 7
#define N_GRAPHS 64
#define SNN_IN  512
#define SNN_HID 1024
#define NCLS    10
#define M_PAD   100096   // 782 * 128
#define MBLK    782
#define NBK     782      // buckets of 128 nodes
#define SORT_CHUNK 4096
#define SORT_NCH   391   // ceil(1600000/4096)
#define XPAIRS  (N_NODES * 64)
#define HPAIRS  (M_PAD * 64)
#define WELEMS  (N_LAYERS * DIM * 256)
#define NQUAD   (N_NODES / 4)     // 25000, exact
#define POOL2_NB 1564    // 64 rows per block
#define SNN_BLKS 256     // 64 graphs x 4 col-chunks of 256
#define SS_PAD  2000384  // padded sorted_src capacity in ints (1.6M + 512*782)

#define AS1 __attribute__((address_space(1)))
#define AS3 __attribute__((address_space(3)))

typedef __attribute__((ext_vector_type(8))) short short8;
typedef __attribute__((ext_vector_type(4))) float f32x4;

__device__ __forceinline__ unsigned int f2bf(float f) {
    unsigned int u = __float_as_uint(f);
    return (u + 0x7fffu + ((u >> 16) & 1u)) >> 16;   // RNE
}
__device__ __forceinline__ float bf2f(unsigned short b) {
    return __uint_as_float(((unsigned int)b) << 16);
}
__device__ __forceinline__ void acc_pair(unsigned int u, float& lo, float& hi) {
    lo += __uint_as_float(u << 16);
    hi += __uint_as_float(u & 0xffff0000u);
}

// ---- setup: fp32 x -> bf16 h0 pairs (node-major), W -> Wt[l][n][k] bf16.
// Zero-inits pooled/counts AND h pad rows [100000,100096) (filler row 100000). ----
__global__ void k_convert(const float* __restrict__ x, const float* __restrict__ wrel,
                          const float* __restrict__ wroot, unsigned int* __restrict__ h,
                          unsigned short* __restrict__ Wt,
                          float* __restrict__ pooled, int* __restrict__ counts) {
    int i = blockIdx.x * blockDim.x + threadIdx.x;
    if (i < N_GRAPHS * 128) pooled[i] = 0.f;
    if (i >= N_GRAPHS * 128 && i < N_GRAPHS * 129) counts[i - N_GRAPHS * 128] = 0;
    if (i < XPAIRS) {
        float2 v = ((const float2*)x)[i];
        h[i] = f2bf(v.x) | (f2bf(v.y) << 16);
    } else if (i < HPAIRS) {
        h[i] = 0u;                       // zero pad rows (incl. filler row 100000)
    } else {
        int idx = i - HPAIRS;
        if (idx < WELEMS) {
            int l = idx >> 15, rem = idx & 32767, n = rem >> 8, k = rem & 255;
            float v = (k < 128) ? wrel[l * 16384 + k * 128 + n]
                                : wroot[l * 16384 + (k - 128) * 128 + n];
            Wt[idx] = (unsigned short)f2bf(v);
        }
    }
}

// ---- sort pass A1: per-chunk LDS histogram over 782 buckets ----
__global__ __launch_bounds__(256) void k_histA(const int* __restrict__ dst,
                                               int* __restrict__ chunk_hist) {
    __shared__ int hist[NBK];
    int b = blockIdx.x, t = threadIdx.x;
    int e0 = b * SORT_CHUNK;
    int e1 = e0 + SORT_CHUNK; if (e1 > N_EDGES) e1 = N_EDGES;
    for (int i = t; i < NBK; i += 256) hist[i] = 0;
    __syncthreads();
    for (int e = e0 + t; e < e1; e += 256) atomicAdd(&hist[dst[e] >> 7], 1);
    __syncthreads();
    for (int i = t; i < NBK; i += 256) chunk_hist[b * NBK + i] = hist[i];
}

// ---- sort pass A2: per-bucket exclusive prefix over the 391 chunk counts ----
__global__ __launch_bounds__(64) void k_colscan(int* __restrict__ chunk_hist,
                                                int* __restrict__ btot) {
    int b = blockIdx.x;
    int lane = threadIdx.x;
    const int C = (SORT_NCH + 63) / 64;   // 7
    int vals[C]; int sum = 0;
    #pragma unroll
    for (int j = 0; j < C; j++) {
        int c = lane * C + j;
        vals[j] = (c < SORT_NCH) ? chunk_hist[c * NBK + b] : 0;
        sum += vals[j];
    }
    int s = sum;
    #pragma unroll
    for (int o = 1; o < 64; o <<= 1) { int t = __shfl_up(s, o); if (lane >= o) s += t; }
    if (lane == 63) btot[b] = s;
    int run = s - sum;
    #pragma unroll
    for (int j = 0; j < C; j++) {
        int c = lane * C + j;
        if (c < SORT_NCH) chunk_hist[c * NBK + b] = run;
        run += vals[j];
    }
}

// ---- tiny cross-bucket scan ----
__global__ __launch_bounds__(256) void k_bscan(const int* __restrict__ btot,
                                               int* __restrict__ bucket_base) {
    __shared__ int wsum[4];
    int tid = threadIdx.x, lane = tid & 63, wid = tid >> 6;
    int i0 = tid * 4;
    int v[4]; int sum = 0;
    #pragma unroll
    for (int j = 0; j < 4; j++) { int i = i0 + j; v[j] = (i < NBK) ? btot[i] : 0; sum += v[j]; }
    int s = sum;
    #pragma unroll
    for (int o = 1; o < 64; o <<= 1) { int t = __shfl_up(s, o); if (lane >= o) s += t; }
    if (lane == 63) wsum[wid] = s;
    __syncthreads();
    if (tid == 0) {
        int acc = 0;
        #pragma unroll
        for (int w = 0; w < 4; w++) { acc += wsum[w]; wsum[w] = acc; }
    }
    __syncthreads();
    int prefix = s - sum + (wid ? wsum[wid - 1] : 0);
    #pragma unroll
    for (int j = 0; j < 4; j++) { int i = i0 + j; if (i < NBK) bucket_base[i] = prefix; prefix += v[j]; }
}

// ---- sort pass A3: scatter via LDS cursors ----
__global__ __launch_bounds__(256) void k_scatterA(const int* __restrict__ src,
                                                  const int* __restrict__ dst,
                                                  const int* __restrict__ chunk_hist,
                                                  const int* __restrict__ bucket_base,
                                                  unsigned int* __restrict__ pairs) {
    __shared__ int lcur[NBK];
    int b = blockIdx.x, t = threadIdx.x;
    int e0 = b * SORT_CHUNK;
    int e1 = e0 + SORT_CHUNK; if (e1 > N_EDGES) e1 = N_EDGES;
    for (int i = t; i < NBK; i += 256) lcur[i] = chunk_hist[b * NBK + i] + bucket_base[i];
    __syncthreads();
    for (int e = e0 + t; e < e1; e += 256) {
        int d = dst[e];
        int bk = d >> 7;
        int pos = atomicAdd(&lcur[bk], 1);
        pairs[pos] = (unsigned int)src[e] | ((unsigned int)(d & 127) << 17);
    }
}

// ---- pass B: per bucket, derive per-node offsets; pads every node's segment
// to a multiple of 4 (filler src = 100000, the zero row). ----
__global__ __launch_bounds__(256) void k_bucketB(const unsigned int* __restrict__ pairs,
                                                 const int* __restrict__ bucket_base,
                                                 const int* __restrict__ btot,
                                                 int* __restrict__ row_off,
                                                 int* __restrict__ ndeg,
                                                 int* __restrict__ sorted_src) {
    __shared__ int lcnt[128];
    __shared__ int loff[128];
    int b = blockIdx.x, t = threadIdx.x;
    int node0 = b << 7;
    int nn = N_NODES - node0; if (nn > 128) nn = 128;
    int base = bucket_base[b];
    int end  = base + btot[b];
    int pbase = ((base + 3) & ~3) + 512 * b;
    if (t < 128) lcnt[t] = 0;
    __syncthreads();
    for (int i = base + t; i < end; i += 256) atomicAdd(&lcnt[pairs[i] >> 17], 1);
    __syncthreads();
    if (t < 64) {
        int v0 = (lcnt[2 * t] + 3) & ~3, v1 = (lcnt[2 * t + 1] + 3) & ~3;
        int s = v0 + v1, ps = s;
        #pragma unroll
        for (int o = 1; o < 64; o <<= 1) { int u = __shfl_up(ps, o); if (t >= o) ps += u; }
        int excl = ps - s;
        loff[2 * t] = excl; loff[2 * t + 1] = excl + v0;
    }
    __syncthreads();
    if (t < nn) {
        int d = lcnt[t];
        row_off[node0 + t] = pbase + loff[t];
        ndeg[node0 + t] = d;
        int pad = (d + 3) & ~3;
        for (int k = d; k < pad; k++) sorted_src[pbase + loff[t] + k] = N_NODES;
    }
    __syncthreads();
    if (t < 128) lcnt[t] = 0;
    __syncthreads();
    for (int i = base + t; i < end; i += 256) {
        unsigned int p = pairs[i];
        int l = p >> 17;
        int pos = atomicAdd(&lcnt[l], 1);
        sorted_src[pbase + loff[l] + pos] = (int)(p & 0x1FFFFu);
    }
}

// ---- aggregation v4: TILE-ALIGNED blocks. Block b owns nodes [128b,128b+128)
// == exactly the A-panel of gemm block b, so agg rows are written on the same
// XCD that re-reads them (782-block grids map block->XCD identically).
// Inner gather loop is the R1-proven one, verbatim. ----
#define GATH(d0, d1, d2, d3, s) \
    d0 = *(const uint4*)(hbl + (size_t)(((unsigned)(s).x) << 8)); \
    d1 = *(const uint4*)(hbl + (size_t)(((unsigned)(s).y) << 8)); \
    d2 = *(const uint4*)(hbl + (size_t)(((unsigned)(s).z) << 8)); \
    d3 = *(const uint4*)(hbl + (size_t)(((unsigned)(s).w) << 8));
#define ACC4(r0, r1, r2, r3) \
    acc_pair((r0).x, a[0], a[1]); acc_pair((r0).y, a[2], a[3]); \
    acc_pair((r0).z, a[4], a[5]); acc_pair((r0).w, a[6], a[7]); \
    acc_pair((r1).x, a[0], a[1]); acc_pair((r1).y, a[2], a[3]); \
    acc_pair((r1).z, a[4], a[5]); acc_pair((r1).w, a[6], a[7]); \
    acc_pair((r2).x, a[0], a[1]); acc_pair((r2).y, a[2], a[3]); \
    acc_pair((r2).z, a[4], a[5]); acc_pair((r2).w, a[6], a[7]); \
    acc_pair((r3).x, a[0], a[1]); acc_pair((r3).y, a[2], a[3]); \
    acc_pair((r3).z, a[4], a[5]); acc_pair((r3).w, a[6], a[7]);

__global__ __launch_bounds__(256) void k_agg(const char* __restrict__ hb,
                                             const int* __restrict__ row_off,
                                             const int* __restrict__ ndeg,
                                             const int4* __restrict__ sorted4,
                                             uint4* __restrict__ agg4) {
    int w = threadIdx.x >> 6;
    int lane = threadIdx.x & 63;
    int sub = lane >> 4, li = lane & 15;
    const char* hbl = hb + li * 16;
    int q0 = blockIdx.x * 32 + w * 8;          // wave handles 8 quads (32 nodes)
    #pragma unroll 1
    for (int j = 0; j < 8; j++) {
        int quad = q0 + j;
        if (quad >= NQUAD) break;
        int node = quad * 4 + sub;                   // < 100000 always
        int beg = row_off[node] >> 2;                // int4 index, 4-aligned
        int nit = (ndeg[node] + 3) >> 2;
        float a[8] = {0.f, 0.f, 0.f, 0.f, 0.f, 0.f, 0.f, 0.f};
        if (nit > 0) {
            int4 sa = sorted4[beg];
            int4 sb = sorted4[beg + 1];              // may read 1 past (slack alloc'd)
            uint4 A0, A1, A2, A3, B0, B1, B2, B3;
            GATH(A0, A1, A2, A3, sa);
            int it = 0;
            for (; it + 2 < nit; it += 2) {
                GATH(B0, B1, B2, B3, sb);
                sa = sorted4[beg + it + 2];
                ACC4(A0, A1, A2, A3);
                GATH(A0, A1, A2, A3, sa);
                sb = sorted4[beg + it + 3];          // may read 1 past
                ACC4(B0, B1, B2, B3);
            }
            if (it + 1 < nit) {
                GATH(B0, B1, B2, B3, sb);
                ACC4(A0, A1, A2, A3);
                ACC4(B0, B1, B2, B3);
            } else {
                ACC4(A0, A1, A2, A3);
            }
        }
        uint4 o;
        o.x = f2bf(a[0]) | (f2bf(a[1]) << 16);
        o.y = f2bf(a[2]) | (f2bf(a[3]) << 16);
        o.z = f2bf(a[4]) | (f2bf(a[5]) << 16);
        o.w = f2bf(a[6]) | (f2bf(a[7]) << 16);
        agg4[(size_t)node * 16 + li] = o;
    }
}

// ---- GraphConv GEMM v3 (R7/R8, kept): wave-private double-buffered A staging,
// zero K-loop barriers, counted vmcnt(8) with sched_barrier guards. ----
__global__ __launch_bounds__(256) void k_gemm(const unsigned short* __restrict__ Ag,
                                              const unsigned short* __restrict__ H,
                                              const unsigned short* __restrict__ Wt,
                                              const float* __restrict__ bias,
                                              unsigned short* __restrict__ Hout) {
    __shared__ char smem[65536];              // 4 waves x 2 bufs x 8KB; Es aliased
    int tid = threadIdx.x;
    int lane = tid & 63, wid = tid >> 6;
    int wr = (wid >> 1) * 64, wc = (wid & 1) * 64;
    int row0 = blockIdx.x * 128;
    int l4 = lane & 15, hq = lane >> 4;
    f32x4 acc[4][4] = {};

    char* wbase = smem + wid * 16384;         // this wave's 2 slab buffers
    const unsigned short* bb = Wt + (size_t)(wc + l4) * 256 + hq * 8;

    auto stage = [&](int buf, int kt) {
        const unsigned short* P = (kt < 2) ? Ag : H;
        int kbase = (kt & 1) * 64;
        #pragma unroll
        for (int j = 0; j < 8; j++) {
            int rowl = 8 * j + (lane >> 3);               // local row 0..63
            int cc = (lane & 7) ^ (rowl & 7);             // source swizzle
            const unsigned short* g = P + (size_t)(row0 + wr + rowl) * 128 + kbase + cc * 8;
            char* l = wbase + buf * 8192 + j * 1024;      // wave-uniform base
            __builtin_amdgcn_global_load_lds((const AS1 unsigned int*)g,
                                             (AS3 unsigned int*)l, 16, 0, 0);
        }
    };

    auto compute = [&](int buf, int kt) {
        const char* base = wbase + buf * 8192;
        #pragma unroll
        for (int s2 = 0; s2 < 2; s2++) {
            int sg = kt * 2 + s2;             // global K-step 0..7
            short8 a[4], b[4];
            #pragma unroll
            for (int mi = 0; mi < 4; mi++) {
                int rowl = l4 + 16 * mi;
                int ch = (s2 * 4 + hq) ^ (rowl & 7);      // swizzled read
                a[mi] = *(const short8*)(base + rowl * 128 + ch * 16);
            }
            #pragma unroll
            for (int ni = 0; ni < 4; ni++)
                b[ni] = *(const short8*)(bb + (size_t)ni * 16 * 256 + sg * 32);
            #pragma unroll
            for (int mi = 0; mi < 4; mi++)
                #pragma unroll
                for (int ni = 0; ni < 4; ni++)
                    acc[mi][ni] = __builtin_amdgcn_mfma_f32_16x16x32_bf16(a[mi], b[ni], acc[mi][ni], 0, 0, 0);
        }
    };

    stage(0, 0);
    #pragma unroll
    for (int kt = 0; kt < 4; kt++) {
        if (kt + 1 < 4) stage((kt + 1) & 1, kt + 1);      // prefetch next slab
        __builtin_amdgcn_sched_barrier(0);
        if (kt < 3) asm volatile("s_waitcnt vmcnt(8)" ::: "memory");  // slab kt landed
        else        asm volatile("s_waitcnt vmcnt(0)" ::: "memory");
        __builtin_amdgcn_sched_barrier(0);
        compute(kt & 1, kt);
    }

    // epilogue (R4-verified): C/D map col=lane&15, row=(lane>>4)*4+reg
    unsigned short* Es = (unsigned short*)smem;   // aliases staging buffers
    int cb = wc + l4;
    int rs = hq * 4;
    #pragma unroll
    for (int p = 0; p < 2; ++p) {
        __syncthreads();
        if (wr == 64 * p) {
            #pragma unroll
            for (int ni = 0; ni < 4; ni++) {
                int col = cb + ni * 16;
                float bn = bias[col];
                #pragma unroll
                for (int mi = 0; mi < 4; mi++) {
                    int rloc = mi * 16 + rs;
                    #pragma unroll
                    for (int rr = 0; rr < 4; rr++) {
                        float v = acc[mi][ni][rr] + bn;
                        v = v > 0.f ? v : 0.f;
                        if (row0 + 64 * p + rloc + rr >= N_NODES) v = 0.f;
                        Es[(rloc + rr) * 144 + col] = (unsigned short)f2bf(v);
                    }
                }
            }
        }
        __syncthreads();
        int rloc = tid >> 2;                  // 0..63
        int c4 = (tid & 3) * 4;               // uint4 chunk base (16 chunks/row)
        uint4* gd = (uint4*)(Hout + (size_t)(row0 + 64 * p + rloc) * 128);
        const uint4* es = (const uint4*)(Es + (size_t)rloc * 144);
        #pragma unroll
        for (int j = 0; j < 4; j++) gd[c4 + j] = es[c4 + j];
    }
}

// ---- pooling + SNN layer 1 v2 (R8-proven): pool = 1564 blocks x 64 rows,
// all 256 threads; snn = 256 blocks (graph x col-chunk). ----
__global__ __launch_bounds__(256) void k_pool_snn(const unsigned short* __restrict__ h,
                                                  const int* __restrict__ batch,
                                                  float* __restrict__ pooled,
                                                  int* __restrict__ counts,
                                                  const float* __restrict__ x,
                                                  const float* __restrict__ w1,
                                                  const float* __restrict__ b1,
                                                  float* __restrict__ snn_out) {
    if (blockIdx.x < POOL2_NB) {
        int start = blockIdx.x * 64;
        if (start >= N_NODES) return;
        __shared__ int bsh[64];
        int t = threadIdx.x;
        int end = start + 64; if (end > N_NODES) end = N_NODES;
        int nn = end - start;
        if (t < nn) bsh[t] = batch[start + t];
        __syncthreads();
        int dim = t & 127, seg = t >> 7;
        int i0 = seg * 32, i1 = i0 + 32; if (i1 > nn) i1 = nn;
        float acc = 0.f; int cur = -1, cnt = 0;
        for (int i = i0; i < i1; i++) {
            int g = bsh[i];                               // wave-uniform
            if (g != cur) {
                if (cur >= 0) {
                    atomicAdd(&pooled[cur * 128 + dim], acc);
                    if (dim == 0) atomicAdd(&counts[cur], cnt);
                }
                cur = g; acc = 0.f; cnt = 0;
            }
            acc += bf2f(h[(size_t)(start + i) * 128 + dim]);
            cnt++;
        }
        if (cur >= 0) {
            atomicAdd(&pooled[cur * 128 + dim], acc);
            if (dim == 0) atomicAdd(&counts[cur], cnt);
        }
    } else {
        int m2 = blockIdx.x - POOL2_NB;                   // 0..255
        int m = m2 >> 2, cc = m2 & 3;
        __shared__ float xs[SNN_IN];
        int tid = threadIdx.x;
        for (int i = tid; i < SNN_IN; i += 256) xs[i] = x[m * SNN_IN + i];
        __syncthreads();
        int c = cc * 256 + tid;
        float a = 0.f;
        for (int k = 0; k < SNN_IN; k++) a += xs[k] * w1[(size_t)k * SNN_HID + c];
        float v = a + b1[c];
        snn_out[m * SNN_HID + c] = v > 0.f ? v : 0.f;
    }
}

// ---- head: gnn logits + snn logits + fusion, one wave per graph ----
__global__ __launch_bounds__(64) void k_head(const float* __restrict__ pooled, const int* __restrict__ counts,
                                             const float* __restrict__ lin_w, const float* __restrict__ lin_b,
                                             const float* __restrict__ snn_h, const float* __restrict__ w2,
                                             const float* __restrict__ b2, const float* __restrict__ fuse_w,
                                             const float* __restrict__ fuse_b, float* __restrict__ out) {
    int m = blockIdx.x, lane = threadIdx.x;
    __shared__ float sm[20];
    float cnt = (float)(counts[m] > 0 ? counts[m] : 1);
    float p0 = pooled[m * 128 + lane] / cnt;
    float p1 = pooled[m * 128 + 64 + lane] / cnt;
    for (int c = 0; c < NCLS; c++) {
        float v = p0 * lin_w[lane * 10 + c] + p1 * lin_w[(lane + 64) * 10 + c];
        #pragma unroll
        for (int o = 32; o > 0; o >>= 1) v += __shfl_down(v, o);
        if (lane == 0) sm[10 + c] = v + lin_b[c];
    }
    for (int c = 0; c < NCLS; c++) {
        float v = 0.f;
        #pragma unroll
        for (int j = 0; j < 16; j++) {
            int k = lane + j * 64;
            v += snn_h[m * SNN_HID + k] * w2[k * 10 + c];
        }
        #pragma unroll
        for (int o = 32; o > 0; o >>= 1) v += __shfl_down(v, o);
        if (lane == 0) sm[c] = 0.85f * (v + b2[c]);
    }
    __syncthreads();
    if (lane < NCLS) {
        float o = fuse_b[lane];
        #pragma unroll
        for (int j = 0; j < 20; j++) o += sm[j] * fuse_w[j * 10 + lane];
        out[m * 10 + lane] = o;
    }
}

extern "C" void kernel_launch(void* const* d_in, const int* in_sizes, int n_in,
                              void* d_out, int out_size, void* d_ws, size_t ws_size,
                              hipStream_t stream) {
    const float* snn_x  = (const float*)d_in[0];
    const float* x      = (const float*)d_in[1];
    const int*   ei     = (const int*)d_in[2];
    const int*   batch  = (const int*)d_in[3];
    const float* w1     = (const float*)d_in[4];
    const float* b1     = (const float*)d_in[5];
    const float* w2     = (const float*)d_in[6];
    const float* b2     = (const float*)d_in[7];
    const float* wrel   = (const float*)d_in[8];
    const float* wroot  = (const float*)d_in[9];
    const float* brel   = (const float*)d_in[10];
    const float* lin_w  = (const float*)d_in[11];
    const float* lin_b  = (const float*)d_in[12];
    const float* fuse_w = (const float*)d_in[13];
    const float* fuse_b = (const float*)d_in[14];
    const int* srcv = ei;
    const int* dstv = ei + N_EDGES;

    char* ws = (char*)d_ws;
    size_t off = 0;
    auto alloc = [&](size_t b) { char* p = ws + off; off = (off + b + 255) & ~(size_t)255; return p; };
    unsigned short* h0   = (unsigned short*)alloc((size_t)M_PAD * 128 * 2);   // 25.6 MB
    unsigned short* h1   = (unsigned short*)alloc((size_t)M_PAD * 128 * 2);   // 25.6 MB
    unsigned short* agg  = (unsigned short*)alloc((size_t)M_PAD * 128 * 2);   // 25.6 MB
    unsigned short* Wt   = (unsigned short*)alloc((size_t)N_LAYERS * 128 * 256 * 2);
    int* sorted_src = (int*)alloc((size_t)SS_PAD * 4 + 16);   // padded + int4-read slack
    unsigned int* pairs = (unsigned int*)alloc((size_t)N_EDGES * 4);
    int* chunk_hist = (int*)alloc((size_t)SORT_NCH * NBK * 4);   // 1.22 MB
    int* row_off    = (int*)alloc((size_t)(N_NODES + 1) * 4);
    int* ndeg       = (int*)alloc((size_t)N_NODES * 4);
    int* btot       = (int*)alloc((size_t)NBK * 4);
    int* bucket_base= (int*)alloc((size_t)NBK * 4);
    float* pooled   = (float*)alloc((size_t)N_GRAPHS * 128 * 4);
    int* counts     = (int*)alloc((size_t)N_GRAPHS * 4);
    float* snn_h    = (float*)alloc((size_t)N_GRAPHS * SNN_HID * 4);

    k_histA<<<SORT_NCH, 256, 0, stream>>>(dstv, chunk_hist);
    k_colscan<<<NBK, 64, 0, stream>>>(chunk_hist, btot);
    k_bscan<<<1, 256, 0, stream>>>(btot, bucket_base);
    k_scatterA<<<SORT_NCH, 256, 0, stream>>>(srcv, dstv, chunk_hist, bucket_base, pairs);
    k_bucketB<<<NBK, 256, 0, stream>>>(pairs, bucket_base, btot, row_off, ndeg, sorted_src);
    k_convert<<<(HPAIRS + WELEMS + 255) / 256, 256, 0, stream>>>(x, wrel, wroot, (unsigned int*)h0,
                                                                 Wt, pooled, counts);

    unsigned short* hc = h0;
    unsigned short* hn = h1;
    for (int l = 0; l < N_LAYERS; l++) {
        k_agg<<<MBLK, 256, 0, stream>>>((const char*)hc, row_off, ndeg,
                                        (const int4*)sorted_src, (uint4*)agg);
        k_gemm<<<MBLK, 256, 0, stream>>>(agg, hc, Wt + (size_t)l * 128 * 256, brel + l * 128, hn);
        unsigned short* t = hc; hc = hn; hn = t;
    }
    k_pool_snn<<<POOL2_NB + SNN_BLKS, 256, 0, stream>>>(hc, batch, pooled, counts,
                                                        snn_x, w1, b1, snn_h);
    k_head<<<N_GRAPHS, 64, 0, stream>>>(pooled, counts, lin_w, lin_b, snn_h, w2, b2, fuse_w, fuse_b,
                                        (float*)d_out);
}

// Round 11
// 841.335 us; speedup vs baseline: 1.0325x; 1.0325x over previous
//
#include <hip/hip_runtime.h>
#include <hip/hip_bf16.h>

#define N_NODES 100000
#define N_EDGES 1600000
#define DIM     128
#define N_LAYERS 7
#define N_GRAPHS 64
#define SNN_IN  512
#define SNN_HID 1024
#define NCLS    10
#define M_PAD   100096   // 782 * 128
#define MBLK    782
#define NBK     782      // buckets of 128 nodes
#define SORT_CHUNK 4096
#define SORT_NCH   391   // ceil(1600000/4096)
#define XPAIRS  (N_NODES * 64)
#define HPAIRS  (M_PAD * 64)
#define WELEMS  (N_LAYERS * DIM * 256)
#define AGG_BLOCKS 2048
#define AGG_WAVES  (AGG_BLOCKS * 4)
#define NQUAD   (N_NODES / 4)     // 25000, exact
#define POOL2_NB 1564    // 64 rows per block
#define SNN_BLKS 256     // 64 graphs x 4 col-chunks of 256
#define SS_PAD  2000384  // padded sorted_src capacity in ints (1.6M + 512*782)

#define AS1 __attribute__((address_space(1)))
#define AS3 __attribute__((address_space(3)))

typedef __attribute__((ext_vector_type(8))) short short8;
typedef __attribute__((ext_vector_type(4))) float f32x4;

__device__ __forceinline__ unsigned int f2bf(float f) {
    unsigned int u = __float_as_uint(f);
    return (u + 0x7fffu + ((u >> 16) & 1u)) >> 16;   // RNE
}
__device__ __forceinline__ float bf2f(unsigned short b) {
    return __uint_as_float(((unsigned int)b) << 16);
}
__device__ __forceinline__ void acc_pair(unsigned int u, float& lo, float& hi) {
    lo += __uint_as_float(u << 16);
    hi += __uint_as_float(u & 0xffff0000u);
}

// ---- setup: fp32 x -> bf16 h0 pairs (node-major), W -> Wt[l][n][k] bf16.
// Zero-inits pooled/counts AND h pad rows [100000,100096) (filler row 100000). ----
__global__ void k_convert(const float* __restrict__ x, const float* __restrict__ wrel,
                          const float* __restrict__ wroot, unsigned int* __restrict__ h,
                          unsigned short* __restrict__ Wt,
                          float* __restrict__ pooled, int* __restrict__ counts) {
    int i = blockIdx.x * blockDim.x + threadIdx.x;
    if (i < N_GRAPHS * 128) pooled[i] = 0.f;
    if (i >= N_GRAPHS * 128 && i < N_GRAPHS * 129) counts[i - N_GRAPHS * 128] = 0;
    if (i < XPAIRS) {
        float2 v = ((const float2*)x)[i];
        h[i] = f2bf(v.x) | (f2bf(v.y) << 16);
    } else if (i < HPAIRS) {
        h[i] = 0u;                       // zero pad rows (incl. filler row 100000)
    } else {
        int idx = i - HPAIRS;
        if (idx < WELEMS) {
            int l = idx >> 15, rem = idx & 32767, n = rem >> 8, k = rem & 255;
            float v = (k < 128) ? wrel[l * 16384 + k * 128 + n]
                                : wroot[l * 16384 + (k - 128) * 128 + n];
            Wt[idx] = (unsigned short)f2bf(v);
        }
    }
}

// ---- sort pass A1: per-chunk LDS histogram over 782 buckets ----
__global__ __launch_bounds__(256) void k_histA(const int* __restrict__ dst,
                                               int* __restrict__ chunk_hist) {
    __shared__ int hist[NBK];
    int b = blockIdx.x, t = threadIdx.x;
    int e0 = b * SORT_CHUNK;
    int e1 = e0 + SORT_CHUNK; if (e1 > N_EDGES) e1 = N_EDGES;
    for (int i = t; i < NBK; i += 256) hist[i] = 0;
    __syncthreads();
    for (int e = e0 + t; e < e1; e += 256) atomicAdd(&hist[dst[e] >> 7], 1);
    __syncthreads();
    for (int i = t; i < NBK; i += 256) chunk_hist[b * NBK + i] = hist[i];
}

// ---- sort pass A2: per-bucket exclusive prefix over the 391 chunk counts ----
__global__ __launch_bounds__(64) void k_colscan(int* __restrict__ chunk_hist,
                                                int* __restrict__ btot) {
    int b = blockIdx.x;
    int lane = threadIdx.x;
    const int C = (SORT_NCH + 63) / 64;   // 7
    int vals[C]; int sum = 0;
    #pragma unroll
    for (int j = 0; j < C; j++) {
        int c = lane * C + j;
        vals[j] = (c < SORT_NCH) ? chunk_hist[c * NBK + b] : 0;
        sum += vals[j];
    }
    int s = sum;
    #pragma unroll
    for (int o = 1; o < 64; o <<= 1) { int t = __shfl_up(s, o); if (lane >= o) s += t; }
    if (lane == 63) btot[b] = s;
    int run = s - sum;
    #pragma unroll
    for (int j = 0; j < C; j++) {
        int c = lane * C + j;
        if (c < SORT_NCH) chunk_hist[c * NBK + b] = run;
        run += vals[j];
    }
}

// ---- tiny cross-bucket scan ----
__global__ __launch_bounds__(256) void k_bscan(const int* __restrict__ btot,
                                               int* __restrict__ bucket_base) {
    __shared__ int wsum[4];
    int tid = threadIdx.x, lane = tid & 63, wid = tid >> 6;
    int i0 = tid * 4;
    int v[4]; int sum = 0;
    #pragma unroll
    for (int j = 0; j < 4; j++) { int i = i0 + j; v[j] = (i < NBK) ? btot[i] : 0; sum += v[j]; }
    int s = sum;
    #pragma unroll
    for (int o = 1; o < 64; o <<= 1) { int t = __shfl_up(s, o); if (lane >= o) s += t; }
    if (lane == 63) wsum[wid] = s;
    __syncthreads();
    if (tid == 0) {
        int acc = 0;
        #pragma unroll
        for (int w = 0; w < 4; w++) { acc += wsum[w]; wsum[w] = acc; }
    }
    __syncthreads();
    int prefix = s - sum + (wid ? wsum[wid - 1] : 0);
    #pragma unroll
    for (int j = 0; j < 4; j++) { int i = i0 + j; if (i < NBK) bucket_base[i] = prefix; prefix += v[j]; }
}

// ---- sort pass A3: scatter via LDS cursors ----
__global__ __launch_bounds__(256) void k_scatterA(const int* __restrict__ src,
                                                  const int* __restrict__ dst,
                                                  const int* __restrict__ chunk_hist,
                                                  const int* __restrict__ bucket_base,
                                                  unsigned int* __restrict__ pairs) {
    __shared__ int lcur[NBK];
    int b = blockIdx.x, t = threadIdx.x;
    int e0 = b * SORT_CHUNK;
    int e1 = e0 + SORT_CHUNK; if (e1 > N_EDGES) e1 = N_EDGES;
    for (int i = t; i < NBK; i += 256) lcur[i] = chunk_hist[b * NBK + i] + bucket_base[i];
    __syncthreads();
    for (int e = e0 + t; e < e1; e += 256) {
        int d = dst[e];
        int bk = d >> 7;
        int pos = atomicAdd(&lcur[bk], 1);
        pairs[pos] = (unsigned int)src[e] | ((unsigned int)(d & 127) << 17);
    }
}

// ---- pass B: per bucket, derive per-node offsets; pads every node's segment
// to a multiple of 4 (filler src = 100000, the zero row). ----
__global__ __launch_bounds__(256) void k_bucketB(const unsigned int* __restrict__ pairs,
                                                 const int* __restrict__ bucket_base,
                                                 const int* __restrict__ btot,
                                                 int* __restrict__ row_off,
                                                 int* __restrict__ ndeg,
                                                 int* __restrict__ sorted_src) {
    __shared__ int lcnt[128];
    __shared__ int loff[128];
    int b = blockIdx.x, t = threadIdx.x;
    int node0 = b << 7;
    int nn = N_NODES - node0; if (nn > 128) nn = 128;
    int base = bucket_base[b];
    int end  = base + btot[b];
    int pbase = ((base + 3) & ~3) + 512 * b;
    if (t < 128) lcnt[t] = 0;
    __syncthreads();
    for (int i = base + t; i < end; i += 256) atomicAdd(&lcnt[pairs[i] >> 17], 1);
    __syncthreads();
    if (t < 64) {
        int v0 = (lcnt[2 * t] + 3) & ~3, v1 = (lcnt[2 * t + 1] + 3) & ~3;
        int s = v0 + v1, ps = s;
        #pragma unroll
        for (int o = 1; o < 64; o <<= 1) { int u = __shfl_up(ps, o); if (t >= o) ps += u; }
        int excl = ps - s;
        loff[2 * t] = excl; loff[2 * t + 1] = excl + v0;
    }
    __syncthreads();
    if (t < nn) {
        int d = lcnt[t];
        row_off[node0 + t] = pbase + loff[t];
        ndeg[node0 + t] = d;
        int pad = (d + 3) & ~3;
        for (int k = d; k < pad; k++) sorted_src[pbase + loff[t] + k] = N_NODES;
    }
    __syncthreads();
    if (t < 128) lcnt[t] = 0;
    __syncthreads();
    for (int i = base + t; i < end; i += 256) {
        unsigned int p = pairs[i];
        int l = p >> 17;
        int pos = atomicAdd(&lcnt[l], 1);
        sorted_src[pbase + loff[l] + pos] = (int)(p & 0x1FFFFu);
    }
}

// ---- aggregation (R1/R8-proven, 59.7us): grid-stride subgroup-per-node,
// aligned int4 index loads, zero-row fillers, 2-deep ping-pong pipeline. ----
#define GATH(d0, d1, d2, d3, s) \
    d0 = *(const uint4*)(hbl + (size_t)(((unsigned)(s).x) << 8)); \
    d1 = *(const uint4*)(hbl + (size_t)(((unsigned)(s).y) << 8)); \
    d2 = *(const uint4*)(hbl + (size_t)(((unsigned)(s).z) << 8)); \
    d3 = *(const uint4*)(hbl + (size_t)(((unsigned)(s).w) << 8));
#define ACC4(r0, r1, r2, r3) \
    acc_pair((r0).x, a[0], a[1]); acc_pair((r0).y, a[2], a[3]); \
    acc_pair((r0).z, a[4], a[5]); acc_pair((r0).w, a[6], a[7]); \
    acc_pair((r1).x, a[0], a[1]); acc_pair((r1).y, a[2], a[3]); \
    acc_pair((r1).z, a[4], a[5]); acc_pair((r1).w, a[6], a[7]); \
    acc_pair((r2).x, a[0], a[1]); acc_pair((r2).y, a[2], a[3]); \
    acc_pair((r2).z, a[4], a[5]); acc_pair((r2).w, a[6], a[7]); \
    acc_pair((r3).x, a[0], a[1]); acc_pair((r3).y, a[2], a[3]); \
    acc_pair((r3).z, a[4], a[5]); acc_pair((r3).w, a[6], a[7]);

__global__ __launch_bounds__(256) void k_agg(const char* __restrict__ hb,
                                             const int* __restrict__ row_off,
                                             const int* __restrict__ ndeg,
                                             const int4* __restrict__ sorted4,
                                             uint4* __restrict__ agg4) {
    int gw = blockIdx.x * 4 + (threadIdx.x >> 6);   // global wave id
    int lane = threadIdx.x & 63;
    int sub = lane >> 4, li = lane & 15;
    const char* hbl = hb + li * 16;
    for (int quad = gw; quad < NQUAD; quad += AGG_WAVES) {
        int node = quad * 4 + sub;                   // < 100000 always (4*25000)
        int beg = row_off[node] >> 2;                // int4 index, 4-aligned
        int nit = (ndeg[node] + 3) >> 2;
        float a[8] = {0.f, 0.f, 0.f, 0.f, 0.f, 0.f, 0.f, 0.f};
        if (nit > 0) {
            int4 sa = sorted4[beg];
            int4 sb = sorted4[beg + 1];              // may read 1 past (slack alloc'd)
            uint4 A0, A1, A2, A3, B0, B1, B2, B3;
            GATH(A0, A1, A2, A3, sa);
            int it = 0;
            for (; it + 2 < nit; it += 2) {
                GATH(B0, B1, B2, B3, sb);
                sa = sorted4[beg + it + 2];
                ACC4(A0, A1, A2, A3);
                GATH(A0, A1, A2, A3, sa);
                sb = sorted4[beg + it + 3];          // may read 1 past
                ACC4(B0, B1, B2, B3);
            }
            if (it + 1 < nit) {
                GATH(B0, B1, B2, B3, sb);
                ACC4(A0, A1, A2, A3);
                ACC4(B0, B1, B2, B3);
            } else {
                ACC4(A0, A1, A2, A3);
            }
        }
        uint4 o;
        o.x = f2bf(a[0]) | (f2bf(a[1]) << 16);
        o.y = f2bf(a[2]) | (f2bf(a[3]) << 16);
        o.z = f2bf(a[4]) | (f2bf(a[5]) << 16);
        o.w = f2bf(a[6]) | (f2bf(a[7]) << 16);
        agg4[(size_t)node * 16 + li] = o;
    }
}

// ---- GraphConv GEMM v3 (R7/R8-proven): wave-private double-buffered A staging,
// zero K-loop barriers, counted vmcnt(8) with sched_barrier guards. ----
__global__ __launch_bounds__(256) void k_gemm(const unsigned short* __restrict__ Ag,
                                              const unsigned short* __restrict__ H,
                                              const unsigned short* __restrict__ Wt,
                                              const float* __restrict__ bias,
                                              unsigned short* __restrict__ Hout) {
    __shared__ char smem[65536];              // 4 waves x 2 bufs x 8KB; Es aliased
    int tid = threadIdx.x;
    int lane = tid & 63, wid = tid >> 6;
    int wr = (wid >> 1) * 64, wc = (wid & 1) * 64;
    int row0 = blockIdx.x * 128;
    int l4 = lane & 15, hq = lane >> 4;
    f32x4 acc[4][4] = {};

    char* wbase = smem + wid * 16384;         // this wave's 2 slab buffers
    const unsigned short* bb = Wt + (size_t)(wc + l4) * 256 + hq * 8;

    auto stage = [&](int buf, int kt) {
        const unsigned short* P = (kt < 2) ? Ag : H;
        int kbase = (kt & 1) * 64;
        #pragma unroll
        for (int j = 0; j < 8; j++) {
            int rowl = 8 * j + (lane >> 3);               // local row 0..63
            int cc = (lane & 7) ^ (rowl & 7);             // source swizzle
            const unsigned short* g = P + (size_t)(row0 + wr + rowl) * 128 + kbase + cc * 8;
            char* l = wbase + buf * 8192 + j * 1024;      // wave-uniform base
            __builtin_amdgcn_global_load_lds((const AS1 unsigned int*)g,
                                             (AS3 unsigned int*)l, 16, 0, 0);
        }
    };

    auto compute = [&](int buf, int kt) {
        const char* base = wbase + buf * 8192;
        #pragma unroll
        for (int s2 = 0; s2 < 2; s2++) {
            int sg = kt * 2 + s2;             // global K-step 0..7
            short8 a[4], b[4];
            #pragma unroll
            for (int mi = 0; mi < 4; mi++) {
                int rowl = l4 + 16 * mi;
                int ch = (s2 * 4 + hq) ^ (rowl & 7);      // swizzled read
                a[mi] = *(const short8*)(base + rowl * 128 + ch * 16);
            }
            #pragma unroll
            for (int ni = 0; ni < 4; ni++)
                b[ni] = *(const short8*)(bb + (size_t)ni * 16 * 256 + sg * 32);
            #pragma unroll
            for (int mi = 0; mi < 4; mi++)
                #pragma unroll
                for (int ni = 0; ni < 4; ni++)
                    acc[mi][ni] = __builtin_amdgcn_mfma_f32_16x16x32_bf16(a[mi], b[ni], acc[mi][ni], 0, 0, 0);
        }
    };

    stage(0, 0);
    #pragma unroll
    for (int kt = 0; kt < 4; kt++) {
        if (kt + 1 < 4) stage((kt + 1) & 1, kt + 1);      // prefetch next slab
        __builtin_amdgcn_sched_barrier(0);
        if (kt < 3) asm volatile("s_waitcnt vmcnt(8)" ::: "memory");  // slab kt landed
        else        asm volatile("s_waitcnt vmcnt(0)" ::: "memory");
        __builtin_amdgcn_sched_barrier(0);
        compute(kt & 1, kt);
    }

    // epilogue (R4-verified): C/D map col=lane&15, row=(lane>>4)*4+reg
    unsigned short* Es = (unsigned short*)smem;   // aliases staging buffers
    int cb = wc + l4;
    int rs = hq * 4;
    #pragma unroll
    for (int p = 0; p < 2; ++p) {
        __syncthreads();
        if (wr == 64 * p) {
            #pragma unroll
            for (int ni = 0; ni < 4; ni++) {
                int col = cb + ni * 16;
                float bn = bias[col];
                #pragma unroll
                for (int mi = 0; mi < 4; mi++) {
                    int rloc = mi * 16 + rs;
                    #pragma unroll
                    for (int rr = 0; rr < 4; rr++) {
                        float v = acc[mi][ni][rr] + bn;
                        v = v > 0.f ? v : 0.f;
                        if (row0 + 64 * p + rloc + rr >= N_NODES) v = 0.f;
                        Es[(rloc + rr) * 144 + col] = (unsigned short)f2bf(v);
                    }
                }
            }
        }
        __syncthreads();
        int rloc = tid >> 2;                  // 0..63
        int c4 = (tid & 3) * 4;               // uint4 chunk base (16 chunks/row)
        uint4* gd = (uint4*)(Hout + (size_t)(row0 + 64 * p + rloc) * 128);
        const uint4* es = (const uint4*)(Es + (size_t)rloc * 144);
        #pragma unroll
        for (int j = 0; j < 4; j++) gd[c4 + j] = es[c4 + j];
    }
}

// ---- pooling + SNN layer 1 v2 (R8-proven): pool = 1564 blocks x 64 rows,
// all 256 threads; snn = 256 blocks (graph x col-chunk). ----
__global__ __launch_bounds__(256) void k_pool_snn(const unsigned short* __restrict__ h,
                                                  const int* __restrict__ batch,
                                                  float* __restrict__ pooled,
                                                  int* __restrict__ counts,
                                                  const float* __restrict__ x,
                                                  const float* __restrict__ w1,
                                                  const float* __restrict__ b1,
                                                  float* __restrict__ snn_out) {
    if (blockIdx.x < POOL2_NB) {
        int start = blockIdx.x * 64;
        if (start >= N_NODES) return;
        __shared__ int bsh[64];
        int t = threadIdx.x;
        int end = start + 64; if (end > N_NODES) end = N_NODES;
        int nn = end - start;
        if (t < nn) bsh[t] = batch[start + t];
        __syncthreads();
        int dim = t & 127, seg = t >> 7;
        int i0 = seg * 32, i1 = i0 + 32; if (i1 > nn) i1 = nn;
        float acc = 0.f; int cur = -1, cnt = 0;
        for (int i = i0; i < i1; i++) {
            int g = bsh[i];                               // wave-uniform
            if (g != cur) {
                if (cur >= 0) {
                    atomicAdd(&pooled[cur * 128 + dim], acc);
                    if (dim == 0) atomicAdd(&counts[cur], cnt);
                }
                cur = g; acc = 0.f; cnt = 0;
            }
            acc += bf2f(h[(size_t)(start + i) * 128 + dim]);
            cnt++;
        }
        if (cur >= 0) {
            atomicAdd(&pooled[cur * 128 + dim], acc);
            if (dim == 0) atomicAdd(&counts[cur], cnt);
        }
    } else {
        int m2 = blockIdx.x - POOL2_NB;                   // 0..255
        int m = m2 >> 2, cc = m2 & 3;
        __shared__ float xs[SNN_IN];
        int tid = threadIdx.x;
        for (int i = tid; i < SNN_IN; i += 256) xs[i] = x[m * SNN_IN + i];
        __syncthreads();
        int c = cc * 256 + tid;
        float a = 0.f;
        for (int k = 0; k < SNN_IN; k++) a += xs[k] * w1[(size_t)k * SNN_HID + c];
        float v = a + b1[c];
        snn_out[m * SNN_HID + c] = v > 0.f ? v : 0.f;
    }
}

// ---- head: gnn logits + snn logits + fusion, one wave per graph ----
__global__ __launch_bounds__(64) void k_head(const float* __restrict__ pooled, const int* __restrict__ counts,
                                             const float* __restrict__ lin_w, const float* __restrict__ lin_b,
                                             const float* __restrict__ snn_h, const float* __restrict__ w2,
                                             const float* __restrict__ b2, const float* __restrict__ fuse_w,
                                             const float* __restrict__ fuse_b, float* __restrict__ out) {
    int m = blockIdx.x, lane = threadIdx.x;
    __shared__ float sm[20];
    float cnt = (float)(counts[m] > 0 ? counts[m] : 1);
    float p0 = pooled[m * 128 + lane] / cnt;
    float p1 = pooled[m * 128 + 64 + lane] / cnt;
    for (int c = 0; c < NCLS; c++) {
        float v = p0 * lin_w[lane * 10 + c] + p1 * lin_w[(lane + 64) * 10 + c];
        #pragma unroll
        for (int o = 32; o > 0; o >>= 1) v += __shfl_down(v, o);
        if (lane == 0) sm[10 + c] = v + lin_b[c];
    }
    for (int c = 0; c < NCLS; c++) {
        float v = 0.f;
        #pragma unroll
        for (int j = 0; j < 16; j++) {
            int k = lane + j * 64;
            v += snn_h[m * SNN_HID + k] * w2[k * 10 + c];
        }
        #pragma unroll
        for (int o = 32; o > 0; o >>= 1) v += __shfl_down(v, o);
        if (lane == 0) sm[c] = 0.85f * (v + b2[c]);
    }
    __syncthreads();
    if (lane < NCLS) {
        float o = fuse_b[lane];
        #pragma unroll
        for (int j = 0; j < 20; j++) o += sm[j] * fuse_w[j * 10 + lane];
        out[m * 10 + lane] = o;
    }
}

extern "C" void kernel_launch(void* const* d_in, const int* in_sizes, int n_in,
                              void* d_out, int out_size, void* d_ws, size_t ws_size,
                              hipStream_t stream) {
    const float* snn_x  = (const float*)d_in[0];
    const float* x      = (const float*)d_in[1];
    const int*   ei     = (const int*)d_in[2];
    const int*   batch  = (const int*)d_in[3];
    const float* w1     = (const float*)d_in[4];
    const float* b1     = (const float*)d_in[5];
    const float* w2     = (const float*)d_in[6];
    const float* b2     = (const float*)d_in[7];
    const float* wrel   = (const float*)d_in[8];
    const float* wroot  = (const float*)d_in[9];
    const float* brel   = (const float*)d_in[10];
    const float* lin_w  = (const float*)d_in[11];
    const float* lin_b  = (const float*)d_in[12];
    const float* fuse_w = (const float*)d_in[13];
    const float* fuse_b = (const float*)d_in[14];
    const int* srcv = ei;
    const int* dstv = ei + N_EDGES;

    char* ws = (char*)d_ws;
    size_t off = 0;
    auto alloc = [&](size_t b) { char* p = ws + off; off = (off + b + 255) & ~(size_t)255; return p; };
    unsigned short* h0   = (unsigned short*)alloc((size_t)M_PAD * 128 * 2);   // 25.6 MB
    unsigned short* h1   = (unsigned short*)alloc((size_t)M_PAD * 128 * 2);   // 25.6 MB
    unsigned short* agg  = (unsigned short*)alloc((size_t)M_PAD * 128 * 2);   // 25.6 MB
    unsigned short* Wt   = (unsigned short*)alloc((size_t)N_LAYERS * 128 * 256 * 2);
    int* sorted_src = (int*)alloc((size_t)SS_PAD * 4 + 16);   // padded + int4-read slack
    unsigned int* pairs = (unsigned int*)alloc((size_t)N_EDGES * 4);
    int* chunk_hist = (int*)alloc((size_t)SORT_NCH * NBK * 4);   // 1.22 MB
    int* row_off    = (int*)alloc((size_t)(N_NODES + 1) * 4);
    int* ndeg       = (int*)alloc((size_t)N_NODES * 4);
    int* btot       = (int*)alloc((size_t)NBK * 4);
    int* bucket_base= (int*)alloc((size_t)NBK * 4);
    float* pooled   = (float*)alloc((size_t)N_GRAPHS * 128 * 4);
    int* counts     = (int*)alloc((size_t)N_GRAPHS * 4);
    float* snn_h    = (float*)alloc((size_t)N_GRAPHS * SNN_HID * 4);

    k_histA<<<SORT_NCH, 256, 0, stream>>>(dstv, chunk_hist);
    k_colscan<<<NBK, 64, 0, stream>>>(chunk_hist, btot);
    k_bscan<<<1, 256, 0, stream>>>(btot, bucket_base);
    k_scatterA<<<SORT_NCH, 256, 0, stream>>>(srcv, dstv, chunk_hist, bucket_base, pairs);
    k_bucketB<<<NBK, 256, 0, stream>>>(pairs, bucket_base, btot, row_off, ndeg, sorted_src);
    k_convert<<<(HPAIRS + WELEMS + 255) / 256, 256, 0, stream>>>(x, wrel, wroot, (unsigned int*)h0,
                                                                 Wt, pooled, counts);

    unsigned short* hc = h0;
    unsigned short* hn = h1;
    for (int l = 0; l < N_LAYERS; l++) {
        k_agg<<<AGG_BLOCKS, 256, 0, stream>>>((const char*)hc, row_off, ndeg,
                                              (const int4*)sorted_src, (uint4*)agg);
        k_gemm<<<MBLK, 256, 0, stream>>>(agg, hc, Wt + (size_t)l * 128 * 256, brel + l * 128, hn);
        unsigned short* t = hc; hc = hn; hn = t;
    }
    k_pool_snn<<<POOL2_NB + SNN_BLKS, 256, 0, stream>>>(hc, batch, pooled, counts,
                                                        snn_x, w1, b1, snn_h);
    k_head<<<N_GRAPHS, 64, 0, stream>>>(pooled, counts, lin_w, lin_b, snn_h, w2, b2, fuse_w, fuse_b,
                                        (float*)d_out);
}